// Round 1
// baseline (690.499 us; speedup 1.0000x reference)
//
#include <hip/hip_runtime.h>
#include <math.h>

#define N_BINS 15

// One 64-lane wave per row. C is assumed <= 128 for the register path
// (problem has C=100); generic fallback re-reads via cache otherwise.
__global__ __launch_bounds__(256) void ece_main(const float* __restrict__ logits,
                                                const int* __restrict__ labels,
                                                float* __restrict__ ws,
                                                int N, int C) {
    __shared__ float s_counts[N_BINS];
    __shared__ float s_conf[N_BINS];
    __shared__ float s_acc[N_BINS];
    const int tid = threadIdx.x;
    if (tid < N_BINS) { s_counts[tid] = 0.f; s_conf[tid] = 0.f; s_acc[tid] = 0.f; }
    __syncthreads();

    const int lane = tid & 63;
    const int wave_in_block = tid >> 6;
    const int waves_per_block = blockDim.x >> 6;
    const long long wave_id = (long long)blockIdx.x * waves_per_block + wave_in_block;
    const long long total_waves = (long long)gridDim.x * waves_per_block;

    if (C <= 128) {
        for (long long row = wave_id; row < N; row += total_waves) {
            const float* rp = logits + row * (long long)C;
            // load the row into registers: lane holds elements lane, lane+64
            const bool h0 = (lane < C);
            const bool h1 = (lane + 64 < C);
            float v0 = h0 ? rp[lane] : -INFINITY;
            float v1 = h1 ? rp[lane + 64] : -INFINITY;

            // local (max, first-index)
            float m; int mi;
            if (v1 > v0) { m = v1; mi = lane + 64; } else { m = v0; mi = lane; }
            // wave butterfly max with first-index tiebreak
            #pragma unroll
            for (int off = 32; off > 0; off >>= 1) {
                float om = __shfl_xor(m, off);
                int   oi = __shfl_xor(mi, off);
                if (om > m || (om == m && oi < mi)) { m = om; mi = oi; }
            }
            // sum of exp(v - max)
            float s = (h0 ? __expf(v0 - m) : 0.f) + (h1 ? __expf(v1 - m) : 0.f);
            #pragma unroll
            for (int off = 32; off > 0; off >>= 1) s += __shfl_xor(s, off);

            if (lane == 0) {
                float conf = 1.0f / s;
                int bin = (int)ceilf(conf * (float)N_BINS) - 1;
                bin = bin < 0 ? 0 : (bin > N_BINS - 1 ? N_BINS - 1 : bin);
                float acc = (mi == labels[row]) ? 1.0f : 0.0f;
                atomicAdd(&s_counts[bin], 1.0f);
                atomicAdd(&s_conf[bin], conf);
                atomicAdd(&s_acc[bin], acc);
            }
        }
    } else {
        // generic fallback (not hit for this problem's shapes)
        for (long long row = wave_id; row < N; row += total_waves) {
            const float* rp = logits + row * (long long)C;
            float m = -INFINITY; int mi = C;
            for (int j = lane; j < C; j += 64) {
                float v = rp[j];
                if (v > m) { m = v; mi = j; }
            }
            #pragma unroll
            for (int off = 32; off > 0; off >>= 1) {
                float om = __shfl_xor(m, off);
                int   oi = __shfl_xor(mi, off);
                if (om > m || (om == m && oi < mi)) { m = om; mi = oi; }
            }
            float s = 0.f;
            for (int j = lane; j < C; j += 64) s += __expf(rp[j] - m);
            #pragma unroll
            for (int off = 32; off > 0; off >>= 1) s += __shfl_xor(s, off);
            if (lane == 0) {
                float conf = 1.0f / s;
                int bin = (int)ceilf(conf * (float)N_BINS) - 1;
                bin = bin < 0 ? 0 : (bin > N_BINS - 1 ? N_BINS - 1 : bin);
                float acc = (mi == labels[row]) ? 1.0f : 0.0f;
                atomicAdd(&s_counts[bin], 1.0f);
                atomicAdd(&s_conf[bin], conf);
                atomicAdd(&s_acc[bin], acc);
            }
        }
    }

    __syncthreads();
    if (tid < N_BINS) {
        atomicAdd(&ws[tid],              s_counts[tid]);
        atomicAdd(&ws[N_BINS + tid],     s_conf[tid]);
        atomicAdd(&ws[2 * N_BINS + tid], s_acc[tid]);
    }
}

__global__ void ece_final(const float* __restrict__ ws, float* __restrict__ out, float invN) {
    if (threadIdx.x == 0 && blockIdx.x == 0) {
        float ece = 0.f;
        for (int b = 0; b < N_BINS; ++b) {
            float c = ws[b];
            if (c > 0.f) {
                float conf_m = ws[N_BINS + b] / c;
                float acc_m  = ws[2 * N_BINS + b] / c;
                ece += fabsf(conf_m - acc_m) * (c * invN);
            }
        }
        out[0] = ece;
    }
}

extern "C" void kernel_launch(void* const* d_in, const int* in_sizes, int n_in,
                              void* d_out, int out_size, void* d_ws, size_t ws_size,
                              hipStream_t stream) {
    const float* logits = (const float*)d_in[0];
    const int*   labels = (const int*)d_in[1];
    const int N = in_sizes[1];
    const int C = in_sizes[0] / N;
    float* ws = (float*)d_ws;

    hipMemsetAsync(ws, 0, 3 * N_BINS * sizeof(float), stream);

    const int threads = 256;
    const int blocks = 2048;   // 8 blocks/CU target; grid-stride over rows
    ece_main<<<blocks, threads, 0, stream>>>(logits, labels, ws, N, C);
    ece_final<<<1, 64, 0, stream>>>(ws, (float*)d_out, 1.0f / (float)N);
}

// Round 2
// 566.015 us; speedup vs baseline: 1.2199x; 1.2199x over previous
//
#include <hip/hip_runtime.h>
#include <math.h>

#define N_BINS 15

// 16 lanes per row (wave = 4 rows per iteration). Specialized for C==100:
// lane sl holds float4 #sl (elements 4sl..4sl+3) and #(16+sl) (elements
// 64+4sl..67+4sl, masked to sl<9 -> covers 64..99 exactly, no OOB).
__global__ __launch_bounds__(256) void ece_main(const float* __restrict__ logits,
                                                const int* __restrict__ labels,
                                                float* __restrict__ ws,
                                                int N, int C) {
    __shared__ float s_counts[N_BINS];
    __shared__ float s_conf[N_BINS];
    __shared__ float s_acc[N_BINS];
    const int tid = threadIdx.x;
    if (tid < N_BINS) { s_counts[tid] = 0.f; s_conf[tid] = 0.f; s_acc[tid] = 0.f; }
    __syncthreads();

    const int sl = tid & 15;                                   // sub-lane within 16-group
    const int group   = (blockIdx.x * blockDim.x + tid) >> 4;  // one group = one row
    const int ngroups = (gridDim.x * blockDim.x) >> 4;

    if (C == 100) {
        const bool h = (sl < 9);
        for (int row = group; row < N; row += ngroups) {
            const float4* rp4 = (const float4*)(logits + (size_t)row * 100);
            float4 a = rp4[sl];
            float4 b;
            if (h) b = rp4[16 + sl];
            else   b = make_float4(-INFINITY, -INFINITY, -INFINITY, -INFINITY);

            // local max / first-argmax over up to 8 register elements
            int base0 = 4 * sl, base1 = 64 + 4 * sl;
            float m = a.x; int mi = base0;
            if (a.y > m) { m = a.y; mi = base0 + 1; }
            if (a.z > m) { m = a.z; mi = base0 + 2; }
            if (a.w > m) { m = a.w; mi = base0 + 3; }
            if (b.x > m) { m = b.x; mi = base1; }
            if (b.y > m) { m = b.y; mi = base1 + 1; }
            if (b.z > m) { m = b.z; mi = base1 + 2; }
            if (b.w > m) { m = b.w; mi = base1 + 3; }

            // 16-lane butterfly (offsets < 16 stay within the group)
            #pragma unroll
            for (int off = 1; off < 16; off <<= 1) {
                float om = __shfl_xor(m, off);
                int   oi = __shfl_xor(mi, off);
                if (om > m || (om == m && oi < mi)) { m = om; mi = oi; }
            }

            // exp-sum from registers (exp(-inf - m) == 0 handles the mask)
            float s = __expf(a.x - m) + __expf(a.y - m) + __expf(a.z - m) + __expf(a.w - m);
            s += __expf(b.x - m) + __expf(b.y - m) + __expf(b.z - m) + __expf(b.w - m);
            #pragma unroll
            for (int off = 1; off < 16; off <<= 1) s += __shfl_xor(s, off);

            if (sl == 0) {
                float conf = 1.0f / s;
                int bin = (int)ceilf(conf * (float)N_BINS) - 1;
                bin = bin < 0 ? 0 : (bin > N_BINS - 1 ? N_BINS - 1 : bin);
                float acc = (mi == labels[row]) ? 1.0f : 0.0f;
                atomicAdd(&s_counts[bin], 1.0f);
                atomicAdd(&s_conf[bin], conf);
                atomicAdd(&s_acc[bin], acc);
            }
        }
    } else {
        // generic fallback: 16-lane strided, two passes via cache
        for (int row = group; row < N; row += ngroups) {
            const float* rp = logits + (size_t)row * C;
            float m = -INFINITY; int mi = C;
            for (int j = sl; j < C; j += 16) {
                float v = rp[j];
                if (v > m) { m = v; mi = j; }
            }
            #pragma unroll
            for (int off = 1; off < 16; off <<= 1) {
                float om = __shfl_xor(m, off);
                int   oi = __shfl_xor(mi, off);
                if (om > m || (om == m && oi < mi)) { m = om; mi = oi; }
            }
            float s = 0.f;
            for (int j = sl; j < C; j += 16) s += __expf(rp[j] - m);
            #pragma unroll
            for (int off = 1; off < 16; off <<= 1) s += __shfl_xor(s, off);
            if (sl == 0) {
                float conf = 1.0f / s;
                int bin = (int)ceilf(conf * (float)N_BINS) - 1;
                bin = bin < 0 ? 0 : (bin > N_BINS - 1 ? N_BINS - 1 : bin);
                float acc = (mi == labels[row]) ? 1.0f : 0.0f;
                atomicAdd(&s_counts[bin], 1.0f);
                atomicAdd(&s_conf[bin], conf);
                atomicAdd(&s_acc[bin], acc);
            }
        }
    }

    __syncthreads();
    if (tid < N_BINS) {
        atomicAdd(&ws[tid],              s_counts[tid]);
        atomicAdd(&ws[N_BINS + tid],     s_conf[tid]);
        atomicAdd(&ws[2 * N_BINS + tid], s_acc[tid]);
    }
}

__global__ void ece_final(const float* __restrict__ ws, float* __restrict__ out, float invN) {
    if (threadIdx.x == 0 && blockIdx.x == 0) {
        float ece = 0.f;
        for (int b = 0; b < N_BINS; ++b) {
            float c = ws[b];
            if (c > 0.f) {
                float conf_m = ws[N_BINS + b] / c;
                float acc_m  = ws[2 * N_BINS + b] / c;
                ece += fabsf(conf_m - acc_m) * (c * invN);
            }
        }
        out[0] = ece;
    }
}

extern "C" void kernel_launch(void* const* d_in, const int* in_sizes, int n_in,
                              void* d_out, int out_size, void* d_ws, size_t ws_size,
                              hipStream_t stream) {
    const float* logits = (const float*)d_in[0];
    const int*   labels = (const int*)d_in[1];
    const int N = in_sizes[1];
    const int C = in_sizes[0] / N;
    float* ws = (float*)d_ws;

    hipMemsetAsync(ws, 0, 3 * N_BINS * sizeof(float), stream);

    const int threads = 256;
    const int blocks = 2048;   // 8 blocks/CU; 32768 row-groups grid-striding over 1M rows
    ece_main<<<blocks, threads, 0, stream>>>(logits, labels, ws, N, C);
    ece_final<<<1, 64, 0, stream>>>(ws, (float*)d_out, 1.0f / (float)N);
}